// Round 5
// baseline (191.885 us; speedup 1.0000x reference)
//
#include <hip/hip_runtime.h>

#define B_G   100
#define N_PER 1000
#define E_PER 12000
#define NTOT  (B_G * N_PER)
#define ETOT  (B_G * E_PER)
#define KSEL  800
#define EPT   12            // ceil(E_PER/1024)

typedef __attribute__((ext_vector_type(8))) short short8;
typedef __attribute__((ext_vector_type(4))) float float4_;

__device__ __forceinline__ unsigned short f2bf(float f) {
    unsigned u = __float_as_uint(f);
    u += 0x7fffu + ((u >> 16) & 1u);          // RNE
    return (unsigned short)(u >> 16);
}
__device__ __forceinline__ float bf2f(unsigned short h) {
    return __uint_as_float(((unsigned)h) << 16);
}

// h1s layout: row n = 128 B = 8 chunks of 16 B; chunk c stored at c ^ (n&7).
// -> A-frag b128 reads spread evenly over all 32 banks (was 16-lane pileup).
__device__ __forceinline__ void load_row_frag(
    const unsigned char* h1s, int src, int kgrp, short8& r0, short8& r1) {
    unsigned a0 = (unsigned)src * 128u + (((unsigned)(kgrp ^ (src & 7))) << 4);
    r0 = *(const short8*)(h1s + a0);          // logical chunk kgrp   (feat kgrp*8..)
    r1 = *(const short8*)(h1s + (a0 ^ 64u));  // logical chunk kgrp+4 (feat 32+kgrp*8..)
}

// ===== whole network, one block per graph, everything LDS-resident ==========
__global__ __launch_bounds__(1024) void k_all(
    const int* __restrict__ ei, const float* __restrict__ ew,
    const float* __restrict__ x,
    const float* __restrict__ w1, const float* __restrict__ b1,
    const float* __restrict__ w2, const float* __restrict__ b2,
    const float* __restrict__ pw,
    const float* __restrict__ l1w, const float* __restrict__ l1b,
    const float* __restrict__ l2w, const float* __restrict__ l2b,
    const float* __restrict__ l3w, const float* __restrict__ l3b,
    unsigned* __restrict__ csr, float* __restrict__ out) {
    __shared__ __align__(16) unsigned char smem[152832];
    unsigned char* h1s = smem;                       // swizzled bf16 h1 / h2
    unsigned short* h1u = (unsigned short*)smem;
    int*   ends = (int*)(smem + 128000);
    float* dl   = (float*)(smem + 132096);
    float* x1b  = (float*)(smem + 136192);
    unsigned char* uA = smem + 136448;

    int b = blockIdx.x, tid = threadIdx.x;
    int wid = tid >> 6, lane = tid & 63;
    int gbase = b * N_PER, ebase = b * E_PER;

    // ---- load this thread's edges once into registers (coalesced) ----
    int esrc[EPT], edst[EPT]; float eww[EPT];
    int ne = (tid < (E_PER - (EPT - 1) * 1024)) ? EPT : EPT - 1;
#pragma unroll
    for (int i = 0; i < EPT; i++) {
        if (i < ne) {
            int e = tid + i * 1024;
            esrc[i] = ei[ebase + e] - gbase;
            edst[i] = ei[ETOT + ebase + e] - gbase;
            eww[i]  = ew[ebase + e];
        }
    }
    float* wsum = (float*)uA;
    int*   posc = (int*)(uA + 4096);
    ends[tid] = 0;
    wsum[tid] = 0.f;
    __syncthreads();
    // ---- count pass ----
#pragma unroll
    for (int i = 0; i < EPT; i++)
        if (i < ne) {
            atomicAdd(&ends[edst[i]], 1);
            atomicAdd(&wsum[edst[i]], eww[i]);
        }
    __syncthreads();
    // ---- shuffle-based inclusive scan of counts ----
    int v = ends[tid];
    int sc = v;
#pragma unroll
    for (int m = 1; m < 64; m <<= 1) {
        int t = __shfl_up(sc, m);
        if (lane >= m) sc += t;
    }
    int* wpart = (int*)x1b;                 // temp use
    if (lane == 63) wpart[wid] = sc;
    __syncthreads();
    if (tid < 16) {
        int s2 = wpart[tid];
#pragma unroll
        for (int m = 1; m < 16; m <<= 1) {
            int t = __shfl_up(s2, m);
            if (tid >= m) s2 += t;
        }
        wpart[tid] = s2;
    }
    __syncthreads();
    int incl = sc + (wid > 0 ? wpart[wid - 1] : 0);
    ends[tid] = incl;
    posc[tid] = incl - v;
    dl[tid] = rsqrtf(wsum[tid] + 1.0f);
    __syncthreads();
    // ---- CSR fill: packed u32 = bf16(cf)<<16 | src ----
#pragma unroll
    for (int i = 0; i < EPT; i++)
        if (i < ne) {
            float cf = dl[esrc[i]] * eww[i] * dl[edst[i]];
            int p = atomicAdd(&posc[edst[i]], 1);
            csr[ebase + p] = ((unsigned)f2bf(cf) << 16) | (unsigned)esrc[i];
        }
    __syncthreads();
    // ---- conv1: gather in 3-dim input space, thread per node ----
    float* aggv = (float*)uA;
    if (tid < N_PER) {
        int s = (tid > 0) ? ends[tid - 1] : 0;
        int e = ends[tid];
        float a0 = 0.f, a1 = 0.f, a2 = 0.f;
        for (int k = s; k < e; k++) {
            unsigned q = csr[ebase + k];
            float cf = __uint_as_float(q & 0xFFFF0000u);
            const float* xs = x + (size_t)(gbase + (int)(q & 0xFFFFu)) * 3;
            a0 += cf * xs[0]; a1 += cf * xs[1]; a2 += cf * xs[2];
        }
        float d2 = dl[tid] * dl[tid];
        const float* xn = x + (size_t)(gbase + tid) * 3;
        aggv[tid * 3 + 0] = a0 + d2 * xn[0];
        aggv[tid * 3 + 1] = a1 + d2 * xn[1];
        aggv[tid * 3 + 2] = a2 + d2 * xn[2];
    }
    __syncthreads();
    // ---- h1 = relu(agg @ W1 + b1), swizzled bf16 into LDS; x1 partials ----
    {
        float w0 = w1[lane], w1v = w1[64 + lane], w2v = w1[128 + lane], bf = b1[lane];
        float* sred = (float*)(uA + 12288);
        float px = 0.f;
        int swoff = (lane & 7);
        for (int node = wid; node < N_PER; node += 16) {
            float a0 = aggv[node * 3], a1 = aggv[node * 3 + 1], a2 = aggv[node * 3 + 2];
            float h = fmaxf(a0 * w0 + a1 * w1v + a2 * w2v + bf, 0.f);
            h1u[node * 64 + ((((lane >> 3) ^ (node & 7))) << 3) + swoff] = f2bf(h);
            px += h;
        }
        sred[wid * 64 + lane] = px;
        __syncthreads();
        if (tid < 64) {
            float t = 0.f;
            for (int r = 0; r < 16; r++) t += sred[r * 64 + tid];
            x1b[tid] = t * (1.0f / N_PER);
        }
    }
    __syncthreads();
    // ---- conv2 aggregation directly in MFMA A-fragment layout ----
    int kgrp = lane >> 4, nloc = lane & 15;
    short8 AfS[4][2];
#pragma unroll
    for (int ti = 0; ti < 4; ti++) {
        int t = wid + ti * 16;
        if (t >= 63) continue;
        int li = t * 16 + nloc;
        bool valid = li < N_PER;
        float acc[16];
        if (valid) {
            float d2 = dl[li] * dl[li];
            short8 r0, r1;
            load_row_frag(h1s, li, kgrp, r0, r1);
#pragma unroll
            for (int j = 0; j < 8; j++) {
                acc[j]     = d2 * bf2f((unsigned short)r0[j]);
                acc[8 + j] = d2 * bf2f((unsigned short)r1[j]);
            }
        } else {
#pragma unroll
            for (int j = 0; j < 16; j++) acc[j] = 0.f;
        }
        int s = 0, cnt = 0;
        if (valid) {
            s = (li > 0) ? ends[li - 1] : 0;
            cnt = ends[li] - s;
        }
        int mx = cnt;
#pragma unroll
        for (int m = 1; m < 16; m <<= 1) mx = max(mx, __shfl_xor(mx, m));
        int base = ebase + s;
        int cl = max(cnt - 1, 0);
        unsigned q = csr[min(base, ETOT - 1)];
        for (int k = 0; k < mx; k++) {
            unsigned qn = csr[min(base + min(k + 1, cl), ETOT - 1)];  // prefetch
            if (k < cnt) {
                int src = (int)(q & 0xFFFFu);
                float cf = __uint_as_float(q & 0xFFFF0000u);
                short8 r0, r1;
                load_row_frag(h1s, src, kgrp, r0, r1);
#pragma unroll
                for (int j = 0; j < 8; j++) {
                    acc[j]     += cf * bf2f((unsigned short)r0[j]);
                    acc[8 + j] += cf * bf2f((unsigned short)r1[j]);
                }
            }
            q = qn;
        }
        short8 a0, a1;
#pragma unroll
        for (int j = 0; j < 8; j++) {
            a0[j] = (short)f2bf(acc[j]);
            a1[j] = (short)f2bf(acc[8 + j]);
        }
        AfS[ti][0] = a0;
        AfS[ti][1] = a1;
    }
    __syncthreads();   // all aggregation done; h1s may now be overwritten
    // ---- W2 via MFMA + epilogue (h2 -> h1s region, scores -> keys) ----
    unsigned long long* keys = (unsigned long long*)uA;
    {
        short8 Bf[2][4];
#pragma unroll
        for (int kh = 0; kh < 2; ++kh)
#pragma unroll
            for (int c = 0; c < 4; ++c) {
                short8 t;
#pragma unroll
                for (int j = 0; j < 8; ++j)
                    t[j] = (short)f2bf(w2[(kh * 32 + kgrp * 8 + j) * 64 + c * 16 + nloc]);
                Bf[kh][c] = t;
            }
        float b2c[4], pwc[4];
#pragma unroll
        for (int c = 0; c < 4; ++c) {
            b2c[c] = b2[c * 16 + nloc];
            pwc[c] = pw[c * 16 + nloc];
        }
        float invn;
        {
            float p = pw[lane], pn = p * p;
#pragma unroll
            for (int m = 32; m; m >>= 1) pn += __shfl_xor(pn, m);
            invn = rsqrtf(pn);
        }
        if (tid >= N_PER) keys[tid] = 0ull;    // pad entries sort last
#pragma unroll
        for (int ti = 0; ti < 4; ti++) {
            int t = wid + ti * 16;
            if (t >= 63) continue;
            float4_ accv[4];
#pragma unroll
            for (int c = 0; c < 4; ++c) accv[c] = (float4_){0.f, 0.f, 0.f, 0.f};
#pragma unroll
            for (int kh = 0; kh < 2; ++kh)
#pragma unroll
                for (int c = 0; c < 4; ++c)
                    accv[c] = __builtin_amdgcn_mfma_f32_16x16x32_bf16(AfS[ti][kh], Bf[kh][c], accv[c], 0, 0, 0);
#pragma unroll
            for (int r2 = 0; r2 < 4; ++r2) {
                int li2 = t * 16 + kgrp * 4 + r2;   // C layout: row=(lane>>4)*4+reg
                bool valid2 = li2 < N_PER;
                float sp = 0.f;
#pragma unroll
                for (int c = 0; c < 4; ++c) {
                    float hv = fmaxf(accv[c][r2] + b2c[c], 0.f);
                    sp += hv * pwc[c];
                    if (valid2) {
                        int f = c * 16 + nloc;
                        h1u[li2 * 64 + ((((f >> 3) ^ (li2 & 7))) << 3) + (f & 7)] = f2bf(hv);
                    }
                }
#pragma unroll
                for (int m = 1; m < 16; m <<= 1) sp += __shfl_xor(sp, m);
                if (valid2 && nloc == 0) {
                    float scv = tanhf(sp * invn);
                    unsigned bits = __float_as_uint(scv);
                    unsigned u = (bits & 0x80000000u) ? ~bits : (bits | 0x80000000u);
                    keys[li2] = ((unsigned long long)u << 32) | (unsigned)(1023 - li2);
                }
            }
        }
    }
    __syncthreads();
    // ---- hybrid bitonic sort: j<64 via shfl (no barrier), j>=64 via LDS ----
    {
        unsigned long long key = keys[tid];
        for (int k = 2; k <= 1024; k <<= 1) {
            for (int j = k >> 1; j > 0; j >>= 1) {
                bool desc = (tid & k) == 0;
                unsigned long long p;
                if (j >= 64) {
                    keys[tid] = key;
                    __syncthreads();
                    p = keys[tid ^ j];
                    __syncthreads();
                } else {
                    p = __shfl_xor(key, j);
                }
                bool low = (tid & j) == 0;
                bool sw = low ? (desc ? (key < p) : (key > p))
                              : (desc ? (p < key) : (p > key));
                if (sw) key = p;
            }
        }
        keys[tid] = key;
    }
    __syncthreads();
    // ---- weighted mean over top-K (h2 from LDS) + MLP ----
    float* red   = (float*)(uA + 8192);
    float* a1buf = (float*)(uA + 12288);
    float* a2buf = (float*)(uA + 12544);
    float* zbuf  = (float*)(uA + 12672);
    {
        int f = tid & 63, w16 = tid >> 6;
        float acc = 0.f;
        for (int r = w16; r < KSEL; r += 16) {
            unsigned long long key = keys[r];
            int idx = 1023 - (int)(key & 0xFFFFFFFFu);
            unsigned u = (unsigned)(key >> 32);
            unsigned bits = (u & 0x80000000u) ? (u & 0x7FFFFFFFu) : ~u;
            float val = __uint_as_float(bits);
            acc += val * bf2f(h1u[idx * 64 + ((((f >> 3) ^ (idx & 7))) << 3) + (f & 7)]);
        }
        red[tid] = acc;
    }
    __syncthreads();
    if (tid < 64) {
        float s2 = 0.f;
        for (int ww = 0; ww < 16; ww++) s2 += red[ww * 64 + tid];
        zbuf[tid] = x1b[tid] + s2 * (1.0f / KSEL);
    }
    __syncthreads();
    if (tid < 64) {
        float a = l1b[tid];
        for (int k = 0; k < 64; k++) a += zbuf[k] * l1w[k * 64 + tid];
        a1buf[tid] = fmaxf(a, 0.f);
    }
    __syncthreads();
    if (tid < 32) {
        float a = l2b[tid];
        for (int k = 0; k < 64; k++) a += a1buf[k] * l2w[k * 32 + tid];
        a2buf[tid] = fmaxf(a, 0.f);
    }
    __syncthreads();
    if (tid == 0) {
        float t = l3b[0];
        for (int k = 0; k < 32; k++) t += a2buf[k] * l3w[k];
        out[b] = 1.0f / (1.0f + expf(-t));
    }
}

extern "C" void kernel_launch(void* const* d_in, const int* in_sizes, int n_in,
                              void* d_out, int out_size, void* d_ws, size_t ws_size,
                              hipStream_t stream) {
    const float* x   = (const float*)d_in[0];
    const int*   ei  = (const int*)d_in[1];
    const float* ew  = (const float*)d_in[2];
    const float* c1w = (const float*)d_in[4];
    const float* c1b = (const float*)d_in[5];
    const float* c2w = (const float*)d_in[6];
    const float* c2b = (const float*)d_in[7];
    const float* pw  = (const float*)d_in[8];
    const float* l1w = (const float*)d_in[9];
    const float* l1b = (const float*)d_in[10];
    const float* l2w = (const float*)d_in[11];
    const float* l2b = (const float*)d_in[12];
    const float* l3w = (const float*)d_in[13];
    const float* l3b = (const float*)d_in[14];
    float* out = (float*)d_out;
    unsigned* csr = (unsigned*)d_ws;
    (void)ws_size; (void)in_sizes; (void)n_in; (void)out_size;

    k_all<<<B_G, 1024, 0, stream>>>(ei, ew, x, c1w, c1b, c2w, c2b, pw,
                                    l1w, l1b, l2w, l2b, l3w, l3b, csr, out);
}